// Round 8
// baseline (202.395 us; speedup 1.0000x reference)
//
#include <hip/hip_runtime.h>
#include <type_traits>
#include <utility>

#define B_ 4
#define T_ 160
#define S_ 80
#define F_ 640
#define H_ 1024
#define V_ 1024

typedef float f32x4 __attribute__((ext_vector_type(4)));
typedef short s16x8 __attribute__((ext_vector_type(8)));
typedef __bf16 bf16x8_t __attribute__((ext_vector_type(8)));

// ---- MFMA wrapper: hedge between V8s (short) and V8y (__bf16) builtin signatures ----
template <typename T, typename = void>
struct MfmaTakes : std::false_type {};
template <typename T>
struct MfmaTakes<T, std::void_t<decltype(__builtin_amdgcn_mfma_f32_16x16x32_bf16(
    std::declval<T>(), std::declval<T>(), std::declval<f32x4>(), 0, 0, 0))>>
    : std::true_type {};

template <typename S8>
__device__ __forceinline__ f32x4 mfma_bf16_16x16x32(S8 a, S8 b, f32x4 c) {
  if constexpr (MfmaTakes<S8>::value) {
    return __builtin_amdgcn_mfma_f32_16x16x32_bf16(a, b, c, 0, 0, 0);
  } else {
    return __builtin_amdgcn_mfma_f32_16x16x32_bf16(
        __builtin_bit_cast(bf16x8_t, a), __builtin_bit_cast(bf16x8_t, b), c, 0, 0, 0);
  }
}

// fp32 -> bf16 round-to-nearest-even (no NaN in this workload)
__device__ __forceinline__ unsigned short f2bf(float x) {
  unsigned int u = __float_as_uint(x);
  u += 0x7FFFu + ((u >> 16) & 1u);
  return (unsigned short)(u >> 16);
}

// ---------------------------------------------------------------------------
// Kernel 1: cast W1,W2 to bf16 in fragment-contiguous layout [K/8][N][8]
// so a B-fragment for mfma_16x16x32 is one 16B global load.
// ---------------------------------------------------------------------------
__global__ __launch_bounds__(256) void prep_weights(const float* __restrict__ W1,
                                                    const float* __restrict__ W2,
                                                    s16x8* __restrict__ W1p,
                                                    s16x8* __restrict__ W2p) {
  const int NW1 = (F_ / 8) * H_;   // 81920 chunks
  const int NW2 = (H_ / 8) * V_;   // 131072 chunks
  int c = blockIdx.x * 256 + threadIdx.x;
  if (c < NW1) {
    int kg = c >> 10, v = c & 1023;
    s16x8 o;
#pragma unroll
    for (int i = 0; i < 8; ++i) o[i] = (short)f2bf(W1[(kg * 8 + i) * H_ + v]);
    W1p[c] = o;
  } else if (c < NW1 + NW2) {
    int c2 = c - NW1;
    int kg = c2 >> 10, v = c2 & 1023;
    s16x8 o;
#pragma unroll
    for (int i = 0; i < 8; ++i) o[i] = (short)f2bf(W2[(kg * 8 + i) * V_ + v]);
    W2p[c2] = o;
  }
}

// ---------------------------------------------------------------------------
// Kernel 2: P = src@W1 + b1 (640 rows), Q = tgt@W1 (320 rows), fp32 out.
// 15 WGs x 512 thr; BM=64, 8 waves col-split (128 cols each); 16x16x32 MFMA.
// (~10 us; not the bottleneck — unchanged.)
// ---------------------------------------------------------------------------
__global__ __launch_bounds__(512, 2) void pq_gemm(const float* __restrict__ src,
                                                  const float* __restrict__ tgt,
                                                  const s16x8* __restrict__ W1p,
                                                  const float* __restrict__ b1,
                                                  float* __restrict__ P,
                                                  float* __restrict__ Q) {
  __shared__ s16x8 a_lds[64 * 80];  // 80 KB: rows m, 80 k-chunks, swizzled
  const int tid = threadIdx.x;
  const int wr = blockIdx.x;
  const int r0 = wr * 64;
  const bool isP = (wr < 10);  // rows 0..639 are src, 640..959 are tgt

  for (int c = tid; c < 64 * 80; c += 512) {
    int m = c / 80, kg8 = c - m * 80;
    int R = r0 + m;
    const float* rowp = isP ? (src + R * F_) : (tgt + (R - 640) * F_);
    const f32x4* p4 = (const f32x4*)(rowp + kg8 * 8);
    f32x4 x0 = p4[0], x1 = p4[1];
    s16x8 o;
#pragma unroll
    for (int i = 0; i < 4; ++i) o[i] = (short)f2bf(x0[i]);
#pragma unroll
    for (int i = 0; i < 4; ++i) o[4 + i] = (short)f2bf(x1[i]);
    a_lds[m * 80 + (kg8 ^ (m & 7))] = o;
  }
  __syncthreads();

  const int l = tid & 63, wv = tid >> 6;
  const int g = l >> 4, cl = l & 15;
  const f32x4 zero = {0.f, 0.f, 0.f, 0.f};
  f32x4 acc[4][8];
#pragma unroll
  for (int rt = 0; rt < 4; ++rt)
#pragma unroll
    for (int ct = 0; ct < 8; ++ct) acc[rt][ct] = zero;

  const s16x8* bbase = W1p + g * 1024 + wv * 128 + cl;
  s16x8 bA[8], bB[8], af[4];
#pragma unroll
  for (int ct = 0; ct < 8; ++ct) bA[ct] = bbase[ct * 16];

  for (int ks = 0; ks < 20; ks += 2) {
#pragma unroll
    for (int ct = 0; ct < 8; ++ct) bB[ct] = bbase[(ks + 1) * 4096 + ct * 16];
#pragma unroll
    for (int rt = 0; rt < 4; ++rt) {
      int m = rt * 16 + cl;
      af[rt] = a_lds[m * 80 + ((ks * 4 + g) ^ (m & 7))];
    }
#pragma unroll
    for (int ct = 0; ct < 8; ++ct)
#pragma unroll
      for (int rt = 0; rt < 4; ++rt)
        acc[rt][ct] = mfma_bf16_16x16x32(af[rt], bA[ct], acc[rt][ct]);
    int ksn = (ks + 2 < 20) ? (ks + 2) : 0;  // dummy reload on last iter
#pragma unroll
    for (int ct = 0; ct < 8; ++ct) bA[ct] = bbase[ksn * 4096 + ct * 16];
#pragma unroll
    for (int rt = 0; rt < 4; ++rt) {
      int m = rt * 16 + cl;
      af[rt] = a_lds[m * 80 + (((ks + 1) * 4 + g) ^ (m & 7))];
    }
#pragma unroll
    for (int ct = 0; ct < 8; ++ct)
#pragma unroll
      for (int rt = 0; rt < 4; ++rt)
        acc[rt][ct] = mfma_bf16_16x16x32(af[rt], bB[ct], acc[rt][ct]);
  }

  float b1v[8];
#pragma unroll
  for (int ct = 0; ct < 8; ++ct) b1v[ct] = isP ? b1[wv * 128 + ct * 16 + cl] : 0.f;
  float* outbase = isP ? P : Q;
  const int orow0 = isP ? r0 : (r0 - 640);
#pragma unroll
  for (int rt = 0; rt < 4; ++rt) {
#pragma unroll
    for (int j = 0; j < 4; ++j) {
      int row = rt * 16 + g * 4 + j;
      float* op = outbase + (size_t)(orow0 + row) * H_ + wv * 128 + cl;
#pragma unroll
      for (int ct = 0; ct < 8; ++ct) op[ct * 16] = acc[rt][ct][j] + b1v[ct];
    }
  }
}

// ---------------------------------------------------------------------------
// Kernel 3: fused h-build + GEMM2 + bias + log_softmax.
// Structure (R7): 1600 WGs x 512 thr (8 waves); 32 rows x 1024 cols per WG;
// h_lds = 64 KB -> 2 WGs/CU (unsynced -> phases overlap).
// R8 K-LOOP: two 4-B-frag phases per k-step. Frag liveness = acc 64 (AGPR)
// + b0[4]+b1[4]=32 + af/afn=16 + addr ~10 = ~122 <= 128-reg cap, so the
// prefetch SURVIVES regalloc (R7's 8+8 dbuf needed ~80 VGPR and got
// serialized at the cap -> latency-exposed, MfmaUtil 26%). Immediate-offset
// loads (frags at +0/256/512/768 B), one address add per k-step.
// setprio(1) around MFMA clusters (T5: role diversity from 2 unsynced WGs).
// Canary: FETCH ~47 MB / WRITE 204.8 MB exact; inflation = spill = revert.
// ---------------------------------------------------------------------------
__global__ __launch_bounds__(512, 2) void joint_main(const float* __restrict__ Pm,
                                                     const float* __restrict__ Qm,
                                                     const s16x8* __restrict__ W2p,
                                                     const float* __restrict__ b2,
                                                     float* __restrict__ out) {
  __shared__ s16x8 h_lds[32 * 128];  // 64 KB exactly -> 2 WGs/CU
  const int tid = threadIdx.x;
  int bx = blockIdx.x;
  int bid = (bx & 7) * 200 + (bx >> 3);  // XCD-contiguous swizzle (1600 % 8 == 0)
  const int b = bid / 400;
  int rem = bid - b * 400;
  const int t0 = (rem / 10) * 4;
  const int s0 = (rem - (rem / 10) * 10) * 8;

  // build h = relu(P[t] + Q[s]) as bf16, swizzled: chunk (m,kg8) -> slot kg8^(m&7)
  for (int c = tid; c < 32 * 128; c += 512) {
    int m = c >> 7, kg8 = c & 127;
    int dt = m >> 3, ds = m & 7;
    const f32x4* p4 = (const f32x4*)(Pm + (size_t)(b * T_ + t0 + dt) * H_ + kg8 * 8);
    const f32x4* q4 = (const f32x4*)(Qm + (size_t)(b * S_ + s0 + ds) * H_ + kg8 * 8);
    f32x4 x0 = p4[0] + q4[0];
    f32x4 x1 = p4[1] + q4[1];
    s16x8 o;
#pragma unroll
    for (int i = 0; i < 4; ++i) o[i] = (short)f2bf(fmaxf(x0[i], 0.f));
#pragma unroll
    for (int i = 0; i < 4; ++i) o[4 + i] = (short)f2bf(fmaxf(x1[i], 0.f));
    h_lds[m * 128 + (kg8 ^ (m & 7))] = o;
  }
  __syncthreads();

  const int l = tid & 63, wv = tid >> 6;   // wv in 0..7, owns cols [wv*128, +128)
  const int g = l >> 4, cl = l & 15;
  const f32x4 zero = {0.f, 0.f, 0.f, 0.f};
  f32x4 acc[2][8];
#pragma unroll
  for (int rt = 0; rt < 2; ++rt)
#pragma unroll
    for (int ct = 0; ct < 8; ++ct) acc[rt][ct] = zero;

  // B: W2p index = kg*1024 + v; kg = ks*4+g, v = wv*128 + ct*16 + cl.
  const s16x8* bb = W2p + g * 1024 + wv * 128 + cl;
  const int m0 = cl, m1 = 16 + cl;
  const int sw0 = m0 & 7, sw1 = m1 & 7;  // == cl&7 both

  s16x8 b0[4], b1[4], af[2], afn[2];
#pragma unroll
  for (int i = 0; i < 4; ++i) b0[i] = bb[i * 16];
  af[0] = h_lds[m0 * 128 + (g ^ sw0)];
  af[1] = h_lds[m1 * 128 + (g ^ sw1)];

  for (int ks = 0; ks < 32; ++ks) {
    const s16x8* base = bb + ks * 4096;
    // phase 0: load cols 64..127 frags of this ks; MFMA cols 0..63
#pragma unroll
    for (int i = 0; i < 4; ++i) b1[i] = base[64 + i * 16];
    __builtin_amdgcn_s_setprio(1);
#pragma unroll
    for (int i = 0; i < 4; ++i) {
      acc[0][i] = mfma_bf16_16x16x32(af[0], b0[i], acc[0][i]);
      acc[1][i] = mfma_bf16_16x16x32(af[1], b0[i], acc[1][i]);
    }
    __builtin_amdgcn_s_setprio(0);
    // phase 1: load next ks cols 0..63 + next A-frags; MFMA cols 64..127
    int ksn = (ks + 1 < 32) ? ks + 1 : 0;  // dummy reload on last iter
    const s16x8* basen = bb + ksn * 4096;
#pragma unroll
    for (int i = 0; i < 4; ++i) b0[i] = basen[i * 16];
    {
      int kc = ksn * 4 + g;
      afn[0] = h_lds[m0 * 128 + (kc ^ sw0)];
      afn[1] = h_lds[m1 * 128 + (kc ^ sw1)];
    }
    __builtin_amdgcn_s_setprio(1);
#pragma unroll
    for (int i = 0; i < 4; ++i) {
      acc[0][4 + i] = mfma_bf16_16x16x32(af[0], b1[i], acc[0][4 + i]);
      acc[1][4 + i] = mfma_bf16_16x16x32(af[1], b1[i], acc[1][4 + i]);
    }
    __builtin_amdgcn_s_setprio(0);
    af[0] = afn[0];
    af[1] = afn[1];
  }

  // ---- epilogue: +b2, row-wise log_softmax across 8 waves, store ----
  __syncthreads();  // all waves done reading h before overlaying reductions
  float* redm = reinterpret_cast<float*>(h_lds);  // [8 waves][32 rows]
  float* reds = redm + 256;                       // [8 waves][32 rows]
  float* gmbuf = reds + 256;                      // [32 rows]
  float* lsebuf = gmbuf + 32;                     // [32 rows]

  // bias
#pragma unroll
  for (int ct = 0; ct < 8; ++ct) {
    float bv = b2[wv * 128 + ct * 16 + cl];
#pragma unroll
    for (int rt = 0; rt < 2; ++rt)
#pragma unroll
      for (int j = 0; j < 4; ++j) acc[rt][ct][j] += bv;
  }

  // per-wave per-row max -> redm (scalar chain, one row at a time)
#pragma unroll
  for (int rt = 0; rt < 2; ++rt)
#pragma unroll
    for (int j = 0; j < 4; ++j) {
      float mx = acc[rt][0][j];
#pragma unroll
      for (int ct = 1; ct < 8; ++ct) mx = fmaxf(mx, acc[rt][ct][j]);
#pragma unroll
      for (int msk = 1; msk < 16; msk <<= 1) mx = fmaxf(mx, __shfl_xor(mx, msk, 64));
      if (cl == 0) redm[wv * 32 + rt * 16 + g * 4 + j] = mx;
    }
  __syncthreads();

  // global row max (threads 0..31)
  if (tid < 32) {
    float mx = redm[tid];
#pragma unroll
    for (int w = 1; w < 8; ++w) mx = fmaxf(mx, redm[w * 32 + tid]);
    gmbuf[tid] = mx;
  }
  __syncthreads();

  // per-wave per-row partial sumexp vs global max -> reds
#pragma unroll
  for (int rt = 0; rt < 2; ++rt)
#pragma unroll
    for (int j = 0; j < 4; ++j) {
      int row = rt * 16 + g * 4 + j;
      float gm = gmbuf[row];
      float ps = 0.f;
#pragma unroll
      for (int ct = 0; ct < 8; ++ct) ps += __expf(acc[rt][ct][j] - gm);
#pragma unroll
      for (int msk = 1; msk < 16; msk <<= 1) ps += __shfl_xor(ps, msk, 64);
      if (cl == 0) reds[wv * 32 + row] = ps;
    }
  __syncthreads();

  // finalize lse per row (threads 0..31)
  if (tid < 32) {
    float s = reds[tid];
#pragma unroll
    for (int w = 1; w < 8; ++w) s += reds[w * 32 + tid];
    lsebuf[tid] = gmbuf[tid] + __logf(s);
  }
  __syncthreads();

  // store
#pragma unroll
  for (int rt = 0; rt < 2; ++rt)
#pragma unroll
    for (int j = 0; j < 4; ++j) {
      int row = rt * 16 + g * 4 + j;
      float lse = lsebuf[row];
      int n = (b * T_ + t0 + (row >> 3)) * S_ + s0 + (row & 7);
      float* op = out + (size_t)n * V_ + wv * 128 + cl;
#pragma unroll
      for (int ct = 0; ct < 8; ++ct) op[ct * 16] = acc[rt][ct][j] - lse;
    }
}

// ---------------------------------------------------------------------------
extern "C" void kernel_launch(void* const* d_in, const int* in_sizes, int n_in,
                              void* d_out, int out_size, void* d_ws, size_t ws_size,
                              hipStream_t stream) {
  const float* src = (const float*)d_in[0];  // [4,160,640]
  const float* tgt = (const float*)d_in[1];  // [4,80,640]
  const float* W1  = (const float*)d_in[2];  // [640,1024]
  const float* b1  = (const float*)d_in[3];  // [1024]
  const float* W2  = (const float*)d_in[4];  // [1024,1024]
  const float* b2  = (const float*)d_in[5];  // [1024]
  float* out = (float*)d_out;

  char* ws = (char*)d_ws;
  s16x8* W1p = (s16x8*)(ws);             // 1,310,720 B
  s16x8* W2p = (s16x8*)(ws + 1310720);   // 2,097,152 B
  float* P   = (float*)(ws + 3407872);   // 2,621,440 B  (src@W1 + b1)
  float* Q   = (float*)(ws + 6029312);   // 1,310,720 B  (tgt@W1)
  // total ws use: 7,340,032 B

  prep_weights<<<832, 256, 0, stream>>>(W1, W2, W1p, W2p);
  pq_gemm<<<15, 512, 0, stream>>>(src, tgt, W1p, b1, P, Q);
  joint_main<<<1600, 512, 0, stream>>>(P, Q, W2p, b2, out);
}

// Round 9
// 201.174 us; speedup vs baseline: 1.0061x; 1.0061x over previous
//
#include <hip/hip_runtime.h>
#include <type_traits>
#include <utility>

#define B_ 4
#define T_ 160
#define S_ 80
#define F_ 640
#define H_ 1024
#define V_ 1024

typedef float f32x4 __attribute__((ext_vector_type(4)));
typedef short s16x8 __attribute__((ext_vector_type(8)));
typedef __bf16 bf16x8_t __attribute__((ext_vector_type(8)));

// ---- MFMA wrapper: hedge between V8s (short) and V8y (__bf16) builtin signatures ----
template <typename T, typename = void>
struct MfmaTakes : std::false_type {};
template <typename T>
struct MfmaTakes<T, std::void_t<decltype(__builtin_amdgcn_mfma_f32_16x16x32_bf16(
    std::declval<T>(), std::declval<T>(), std::declval<f32x4>(), 0, 0, 0))>>
    : std::true_type {};

template <typename S8>
__device__ __forceinline__ f32x4 mfma_bf16_16x16x32(S8 a, S8 b, f32x4 c) {
  if constexpr (MfmaTakes<S8>::value) {
    return __builtin_amdgcn_mfma_f32_16x16x32_bf16(a, b, c, 0, 0, 0);
  } else {
    return __builtin_amdgcn_mfma_f32_16x16x32_bf16(
        __builtin_bit_cast(bf16x8_t, a), __builtin_bit_cast(bf16x8_t, b), c, 0, 0, 0);
  }
}

// fp32 -> bf16 round-to-nearest-even (no NaN in this workload)
__device__ __forceinline__ unsigned short f2bf(float x) {
  unsigned int u = __float_as_uint(x);
  u += 0x7FFFu + ((u >> 16) & 1u);
  return (unsigned short)(u >> 16);
}

// ---------------------------------------------------------------------------
// Kernel 1: cast W1,W2 to bf16 in fragment-contiguous layout [K/8][N][8]
// so a B-fragment for mfma_16x16x32 is one 16B global load.
// ---------------------------------------------------------------------------
__global__ __launch_bounds__(256) void prep_weights(const float* __restrict__ W1,
                                                    const float* __restrict__ W2,
                                                    s16x8* __restrict__ W1p,
                                                    s16x8* __restrict__ W2p) {
  const int NW1 = (F_ / 8) * H_;   // 81920 chunks
  const int NW2 = (H_ / 8) * V_;   // 131072 chunks
  int c = blockIdx.x * 256 + threadIdx.x;
  if (c < NW1) {
    int kg = c >> 10, v = c & 1023;
    s16x8 o;
#pragma unroll
    for (int i = 0; i < 8; ++i) o[i] = (short)f2bf(W1[(kg * 8 + i) * H_ + v]);
    W1p[c] = o;
  } else if (c < NW1 + NW2) {
    int c2 = c - NW1;
    int kg = c2 >> 10, v = c2 & 1023;
    s16x8 o;
#pragma unroll
    for (int i = 0; i < 8; ++i) o[i] = (short)f2bf(W2[(kg * 8 + i) * V_ + v]);
    W2p[c2] = o;
  }
}

// ---------------------------------------------------------------------------
// Kernel 2: P = src@W1 + b1 (640 rows), Q = tgt@W1 (320 rows), fp32 out.
// 15 WGs x 512 thr; BM=64, 8 waves col-split (128 cols each); 16x16x32 MFMA.
// (~10 us; not the bottleneck — unchanged.)
// ---------------------------------------------------------------------------
__global__ __launch_bounds__(512, 2) void pq_gemm(const float* __restrict__ src,
                                                  const float* __restrict__ tgt,
                                                  const s16x8* __restrict__ W1p,
                                                  const float* __restrict__ b1,
                                                  float* __restrict__ P,
                                                  float* __restrict__ Q) {
  __shared__ s16x8 a_lds[64 * 80];  // 80 KB: rows m, 80 k-chunks, swizzled
  const int tid = threadIdx.x;
  const int wr = blockIdx.x;
  const int r0 = wr * 64;
  const bool isP = (wr < 10);  // rows 0..639 are src, 640..959 are tgt

  for (int c = tid; c < 64 * 80; c += 512) {
    int m = c / 80, kg8 = c - m * 80;
    int R = r0 + m;
    const float* rowp = isP ? (src + R * F_) : (tgt + (R - 640) * F_);
    const f32x4* p4 = (const f32x4*)(rowp + kg8 * 8);
    f32x4 x0 = p4[0], x1 = p4[1];
    s16x8 o;
#pragma unroll
    for (int i = 0; i < 4; ++i) o[i] = (short)f2bf(x0[i]);
#pragma unroll
    for (int i = 0; i < 4; ++i) o[4 + i] = (short)f2bf(x1[i]);
    a_lds[m * 80 + (kg8 ^ (m & 7))] = o;
  }
  __syncthreads();

  const int l = tid & 63, wv = tid >> 6;
  const int g = l >> 4, cl = l & 15;
  const f32x4 zero = {0.f, 0.f, 0.f, 0.f};
  f32x4 acc[4][8];
#pragma unroll
  for (int rt = 0; rt < 4; ++rt)
#pragma unroll
    for (int ct = 0; ct < 8; ++ct) acc[rt][ct] = zero;

  const s16x8* bbase = W1p + g * 1024 + wv * 128 + cl;
  s16x8 bA[8], bB[8], af[4];
#pragma unroll
  for (int ct = 0; ct < 8; ++ct) bA[ct] = bbase[ct * 16];

  for (int ks = 0; ks < 20; ks += 2) {
#pragma unroll
    for (int ct = 0; ct < 8; ++ct) bB[ct] = bbase[(ks + 1) * 4096 + ct * 16];
#pragma unroll
    for (int rt = 0; rt < 4; ++rt) {
      int m = rt * 16 + cl;
      af[rt] = a_lds[m * 80 + ((ks * 4 + g) ^ (m & 7))];
    }
#pragma unroll
    for (int ct = 0; ct < 8; ++ct)
#pragma unroll
      for (int rt = 0; rt < 4; ++rt)
        acc[rt][ct] = mfma_bf16_16x16x32(af[rt], bA[ct], acc[rt][ct]);
    int ksn = (ks + 2 < 20) ? (ks + 2) : 0;  // dummy reload on last iter
#pragma unroll
    for (int ct = 0; ct < 8; ++ct) bA[ct] = bbase[ksn * 4096 + ct * 16];
#pragma unroll
    for (int rt = 0; rt < 4; ++rt) {
      int m = rt * 16 + cl;
      af[rt] = a_lds[m * 80 + (((ks + 1) * 4 + g) ^ (m & 7))];
    }
#pragma unroll
    for (int ct = 0; ct < 8; ++ct)
#pragma unroll
      for (int rt = 0; rt < 4; ++rt)
        acc[rt][ct] = mfma_bf16_16x16x32(af[rt], bB[ct], acc[rt][ct]);
  }

  float b1v[8];
#pragma unroll
  for (int ct = 0; ct < 8; ++ct) b1v[ct] = isP ? b1[wv * 128 + ct * 16 + cl] : 0.f;
  float* outbase = isP ? P : Q;
  const int orow0 = isP ? r0 : (r0 - 640);
#pragma unroll
  for (int rt = 0; rt < 4; ++rt) {
#pragma unroll
    for (int j = 0; j < 4; ++j) {
      int row = rt * 16 + g * 4 + j;
      float* op = outbase + (size_t)(orow0 + row) * H_ + wv * 128 + cl;
#pragma unroll
      for (int ct = 0; ct < 8; ++ct) op[ct * 16] = acc[rt][ct][j] + b1v[ct];
    }
  }
}

// ---------------------------------------------------------------------------
// Kernel 3: fused h-build + GEMM2 + bias + log_softmax.
// Structure (R7): 1600 WGs x 512 thr (8 waves); 32 rows x 1024 cols per WG;
// 2 WGs/CU (unsynced -> phases overlap).
// R9 K-LOOP: kill addressing VALU (R5-R8 all showed VALUBusy ~= MfmaUtil
// ~26% — the VALU pipe competes with MFMA for issue).
//  * LDS A-tile: +1-slot PADDING ([32][129], row stride 2064 B) instead of
//    XOR swizzle. Bank-free (lane cl -> bank 4cl%32, 2-way = free) AND the
//    read address is base_reg + compile-time imm -> ZERO VALU per A-read.
//  * K-loop FULLY UNROLLED (ks compile-time): B addresses fold to
//    base+const, A-reads use offset immediates, no loop overhead.
// LDS 66 KB <= 80 KB/WG keeps 2 WGs/CU. Liveness: acc 64 AGPR + b0/b1 32 +
// A-frags ~12 + addr ~8 < 128-reg cap.
// Canary: FETCH ~50 MB / WRITE 204.8 MB / LDS <= 80 KB; inflation = revert.
// ---------------------------------------------------------------------------
__global__ __launch_bounds__(512, 2) void joint_main(const float* __restrict__ Pm,
                                                     const float* __restrict__ Qm,
                                                     const s16x8* __restrict__ W2p,
                                                     const float* __restrict__ b2,
                                                     float* __restrict__ out) {
  __shared__ s16x8 h_lds[32 * 129];  // 66048 B, padded rows (129 chunks/row)
  const int tid = threadIdx.x;
  int bx = blockIdx.x;
  int bid = (bx & 7) * 200 + (bx >> 3);  // XCD-contiguous swizzle (1600 % 8 == 0)
  const int b = bid / 400;
  int rem = bid - b * 400;
  const int t0 = (rem / 10) * 4;
  const int s0 = (rem - (rem / 10) * 10) * 8;

  // build h = relu(P[t] + Q[s]) as bf16 into padded rows
  for (int c = tid; c < 32 * 128; c += 512) {
    int m = c >> 7, kg8 = c & 127;
    int dt = m >> 3, ds = m & 7;
    const f32x4* p4 = (const f32x4*)(Pm + (size_t)(b * T_ + t0 + dt) * H_ + kg8 * 8);
    const f32x4* q4 = (const f32x4*)(Qm + (size_t)(b * S_ + s0 + ds) * H_ + kg8 * 8);
    f32x4 x0 = p4[0] + q4[0];
    f32x4 x1 = p4[1] + q4[1];
    s16x8 o;
#pragma unroll
    for (int i = 0; i < 4; ++i) o[i] = (short)f2bf(fmaxf(x0[i], 0.f));
#pragma unroll
    for (int i = 0; i < 4; ++i) o[4 + i] = (short)f2bf(fmaxf(x1[i], 0.f));
    h_lds[m * 129 + kg8] = o;
  }
  __syncthreads();

  const int l = tid & 63, wv = tid >> 6;   // wv in 0..7, owns cols [wv*128, +128)
  const int g = l >> 4, cl = l & 15;
  f32x4 acc[2][8];
#pragma unroll
  for (int rt = 0; rt < 2; ++rt)
#pragma unroll
    for (int ct = 0; ct < 8; ++ct) acc[rt][ct] = {0.f, 0.f, 0.f, 0.f};

  // B: W2p index = (ks*4+g)*1024 + wv*128 + ct*16 + cl  (ks compile-time)
  const s16x8* bb = W2p + g * 1024 + wv * 128 + cl;
  // A: padded-row bases (pure immediate offsets per k-step: +ks*4 chunks)
  const s16x8* a0p = h_lds + cl * 129 + g;
  const s16x8* a1p = h_lds + (16 + cl) * 129 + g;

  s16x8 b0[4], b1[4], af0, af1;
#pragma unroll
  for (int i = 0; i < 4; ++i) b0[i] = bb[i * 16];
  af0 = a0p[0];
  af1 = a1p[0];

#pragma unroll
  for (int ks = 0; ks < 32; ++ks) {
    // phase 0: load this ks' cols 64..127 frags; MFMA cols 0..63
#pragma unroll
    for (int i = 0; i < 4; ++i) b1[i] = bb[ks * 4096 + 64 + i * 16];
    __builtin_amdgcn_s_setprio(1);
#pragma unroll
    for (int i = 0; i < 4; ++i) {
      acc[0][i] = mfma_bf16_16x16x32(af0, b0[i], acc[0][i]);
      acc[1][i] = mfma_bf16_16x16x32(af1, b0[i], acc[1][i]);
    }
    __builtin_amdgcn_s_setprio(0);
    // phase 1: load next ks cols 0..63 + next A-frags; MFMA cols 64..127
    const int ksn = (ks + 1 < 32) ? ks + 1 : 0;  // compile-time select
#pragma unroll
    for (int i = 0; i < 4; ++i) b0[i] = bb[ksn * 4096 + i * 16];
    s16x8 afn0 = a0p[ksn * 4];
    s16x8 afn1 = a1p[ksn * 4];
    __builtin_amdgcn_s_setprio(1);
#pragma unroll
    for (int i = 0; i < 4; ++i) {
      acc[0][4 + i] = mfma_bf16_16x16x32(af0, b1[i], acc[0][4 + i]);
      acc[1][4 + i] = mfma_bf16_16x16x32(af1, b1[i], acc[1][4 + i]);
    }
    __builtin_amdgcn_s_setprio(0);
    af0 = afn0;
    af1 = afn1;
  }

  // ---- epilogue: +b2, row-wise log_softmax across 8 waves, store ----
  __syncthreads();  // all waves done reading h before overlaying reductions
  float* redm = reinterpret_cast<float*>(h_lds);  // [8 waves][32 rows]
  float* reds = redm + 256;                       // [8 waves][32 rows]
  float* gmbuf = reds + 256;                      // [32 rows]
  float* lsebuf = gmbuf + 32;                     // [32 rows]

  // bias
#pragma unroll
  for (int ct = 0; ct < 8; ++ct) {
    float bv = b2[wv * 128 + ct * 16 + cl];
#pragma unroll
    for (int rt = 0; rt < 2; ++rt)
#pragma unroll
      for (int j = 0; j < 4; ++j) acc[rt][ct][j] += bv;
  }

  // per-wave per-row max -> redm (scalar chain, one row at a time)
#pragma unroll
  for (int rt = 0; rt < 2; ++rt)
#pragma unroll
    for (int j = 0; j < 4; ++j) {
      float mx = acc[rt][0][j];
#pragma unroll
      for (int ct = 1; ct < 8; ++ct) mx = fmaxf(mx, acc[rt][ct][j]);
#pragma unroll
      for (int msk = 1; msk < 16; msk <<= 1) mx = fmaxf(mx, __shfl_xor(mx, msk, 64));
      if (cl == 0) redm[wv * 32 + rt * 16 + g * 4 + j] = mx;
    }
  __syncthreads();

  // global row max (threads 0..31)
  if (tid < 32) {
    float mx = redm[tid];
#pragma unroll
    for (int w = 1; w < 8; ++w) mx = fmaxf(mx, redm[w * 32 + tid]);
    gmbuf[tid] = mx;
  }
  __syncthreads();

  // per-wave per-row partial sumexp vs global max -> reds
#pragma unroll
  for (int rt = 0; rt < 2; ++rt)
#pragma unroll
    for (int j = 0; j < 4; ++j) {
      int row = rt * 16 + g * 4 + j;
      float gm = gmbuf[row];
      float ps = 0.f;
#pragma unroll
      for (int ct = 0; ct < 8; ++ct) ps += __expf(acc[rt][ct][j] - gm);
#pragma unroll
      for (int msk = 1; msk < 16; msk <<= 1) ps += __shfl_xor(ps, msk, 64);
      if (cl == 0) reds[wv * 32 + row] = ps;
    }
  __syncthreads();

  // finalize lse per row (threads 0..31)
  if (tid < 32) {
    float s = reds[tid];
#pragma unroll
    for (int w = 1; w < 8; ++w) s += reds[w * 32 + tid];
    lsebuf[tid] = gmbuf[tid] + __logf(s);
  }
  __syncthreads();

  // store
#pragma unroll
  for (int rt = 0; rt < 2; ++rt)
#pragma unroll
    for (int j = 0; j < 4; ++j) {
      int row = rt * 16 + g * 4 + j;
      float lse = lsebuf[row];
      int n = (b * T_ + t0 + (row >> 3)) * S_ + s0 + (row & 7);
      float* op = out + (size_t)n * V_ + wv * 128 + cl;
#pragma unroll
      for (int ct = 0; ct < 8; ++ct) op[ct * 16] = acc[rt][ct][j] - lse;
    }
}

// ---------------------------------------------------------------------------
extern "C" void kernel_launch(void* const* d_in, const int* in_sizes, int n_in,
                              void* d_out, int out_size, void* d_ws, size_t ws_size,
                              hipStream_t stream) {
  const float* src = (const float*)d_in[0];  // [4,160,640]
  const float* tgt = (const float*)d_in[1];  // [4,80,640]
  const float* W1  = (const float*)d_in[2];  // [640,1024]
  const float* b1  = (const float*)d_in[3];  // [1024]
  const float* W2  = (const float*)d_in[4];  // [1024,1024]
  const float* b2  = (const float*)d_in[5];  // [1024]
  float* out = (float*)d_out;

  char* ws = (char*)d_ws;
  s16x8* W1p = (s16x8*)(ws);             // 1,310,720 B
  s16x8* W2p = (s16x8*)(ws + 1310720);   // 2,097,152 B
  float* P   = (float*)(ws + 3407872);   // 2,621,440 B  (src@W1 + b1)
  float* Q   = (float*)(ws + 6029312);   // 1,310,720 B  (tgt@W1)
  // total ws use: 7,340,032 B

  prep_weights<<<832, 256, 0, stream>>>(W1, W2, W1p, W2p);
  pq_gemm<<<15, 512, 0, stream>>>(src, tgt, W1p, b1, P, Q);
  joint_main<<<1600, 512, 0, stream>>>(P, Q, W2p, b2, out);
}